// Round 1
// baseline (96247.382 us; speedup 1.0000x reference)
//
#include <hip/hip_runtime.h>
#include <stdint.h>

typedef unsigned int u32;
typedef unsigned long long u64;

#define NBLK 256
#define NTHR 256
#define Bz 4
#define Tz 128
#define Hz 1024
#define Ez 512
#define Az 512
#define Vz 16000
#define NSTEPS 512
#define HP 1028   // padded LDS row stride (floats): 1028 % 32 == 4 -> conflict-free b-lanes

// ---------------- ws layout (bytes) ----------------
// [0,      16384)  ctrl u32s: grp[g] @ u32 idx g*16 (g<16), root @ 256, gen @ 320
// [16384,  32768)  h      [4][1024] f32
// [32768,  40960)  attn   [4][512]  f32
// [40960,  49152)  amax   [256][4]  u64
// [49152,  51200)  score  [4][128]  f32
// [51200,  59392)  qh     [4][512]  f32
// [59392, +2MB)    enc_outs [4][128][1024] f32
// then             P_t    [4][512][128] f32   (P[b][a][t] = sum_k W_av[a][k]*enc_outs[b][t][k])

__device__ __forceinline__ float sigf(float x) { return 1.0f / (1.0f + expf(-x)); }

// k-serial dot: w global row, v LDS (or global) vector, n4 = n/4 (multiple of 4)
__device__ __forceinline__ float dotk(const float* __restrict__ w,
                                      const float* __restrict__ v, int n4) {
  const float4* __restrict__ w4 = (const float4*)w;
  const float4* __restrict__ v4 = (const float4*)v;
  float4 a0 = make_float4(0.f, 0.f, 0.f, 0.f), a1 = a0, a2 = a0, a3 = a0;
  for (int i = 0; i < n4; i += 4) {
    float4 w0 = w4[i + 0], x0 = v4[i + 0];
    float4 w1 = w4[i + 1], x1 = v4[i + 1];
    float4 w2 = w4[i + 2], x2 = v4[i + 2];
    float4 w3 = w4[i + 3], x3 = v4[i + 3];
    a0.x += w0.x * x0.x; a0.y += w0.y * x0.y; a0.z += w0.z * x0.z; a0.w += w0.w * x0.w;
    a1.x += w1.x * x1.x; a1.y += w1.y * x1.y; a1.z += w1.z * x1.z; a1.w += w1.w * x1.w;
    a2.x += w2.x * x2.x; a2.y += w2.y * x2.y; a2.z += w2.z * x2.z; a2.w += w2.w * x2.w;
    a3.x += w3.x * x3.x; a3.y += w3.y * x3.y; a3.z += w3.z * x3.z; a3.w += w3.w * x3.w;
  }
  a0.x += a1.x; a0.y += a1.y; a0.z += a1.z; a0.w += a1.w;
  a2.x += a3.x; a2.y += a3.y; a2.z += a3.z; a2.w += a3.w;
  a0.x += a2.x; a0.y += a2.y; a0.z += a2.z; a0.w += a2.w;
  return (a0.x + a0.y) + (a0.z + a0.w);
}

// two-level grid barrier, monotonic epochs (state zeroed by hipMemsetAsync before launch)
__device__ __forceinline__ void gridbar(u32* ctrl, int epoch) {
  __syncthreads();
  if (threadIdx.x == 0) {
    const u32 target = (u32)epoch * 16u;
    u32* grp = ctrl + ((blockIdx.x >> 4) * 16);
    u32 v = __hip_atomic_fetch_add(grp, 1u, __ATOMIC_ACQ_REL, __HIP_MEMORY_SCOPE_AGENT);
    if (v == target - 1u) {
      u32 r = __hip_atomic_fetch_add(ctrl + 256, 1u, __ATOMIC_ACQ_REL, __HIP_MEMORY_SCOPE_AGENT);
      if (r == target - 1u)
        __hip_atomic_store(ctrl + 320, (u32)epoch, __ATOMIC_RELEASE, __HIP_MEMORY_SCOPE_AGENT);
    }
    while (__hip_atomic_load(ctrl + 320, __ATOMIC_ACQUIRE, __HIP_MEMORY_SCOPE_AGENT) < (u32)epoch)
      __builtin_amdgcn_s_sleep(1);
  }
  __syncthreads();
}

__global__ void __launch_bounds__(NTHR, 1) seq2seq_kernel(
    const int* __restrict__ inputs,
    const float* __restrict__ enc_emb, const float* __restrict__ enc_Wih,
    const float* __restrict__ enc_Whh, const float* __restrict__ enc_bih,
    const float* __restrict__ enc_bhh,
    const float* __restrict__ dec_emb, const float* __restrict__ dec_Wih,
    const float* __restrict__ dec_Whh, const float* __restrict__ dec_bih,
    const float* __restrict__ dec_bhh,
    const float* __restrict__ W_av, const float* __restrict__ b_av,
    const float* __restrict__ W_cls, const float* __restrict__ b_cls,
    float* __restrict__ out, char* __restrict__ ws) {
  const int tid = threadIdx.x;
  const int bid = blockIdx.x;

  u32* ctrl = (u32*)ws;
  float* h_g = (float*)(ws + 16384);
  float* av_g = (float*)(ws + 32768);
  u64* amax_g = (u64*)(ws + 40960);
  float* score_g = (float*)(ws + 49152);
  float* qh_g = (float*)(ws + 51200);
  float* encout_g = (float*)(ws + 59392);
  float* pt_g = encout_g + Bz * Tz * Hz;
  float* out_pred = out;                        // [512][4][16000]
  float* out_aw = out + (long)NSTEPS * Bz * Vz; // [512][4][128]

  __shared__ __align__(16) float x_s[Bz][HP];
  __shared__ __align__(16) float h_s[Bz][HP];
  __shared__ float g_s[Bz][6][4];
  __shared__ int ids_s[Bz];
  __shared__ __align__(16) float e_s[Bz][132];
  __shared__ float sinv_s[Bz];
  __shared__ __align__(16) float at_s[Bz][516];
  __shared__ u64 am_s[Bz][64];

  int epoch = 0;
  const int jbase = bid * 4; // this block's 4 hidden dims (1024/256)

  // ================= encoder: 128 GRU steps =================
  for (int t = 0; t < Tz; ++t) {
    for (int idx = tid; idx < Bz * Ez; idx += NTHR) {
      int b = idx >> 9, k = idx & 511;
      x_s[b][k] = enc_emb[(long)inputs[b * Tz + t] * Ez + k];
    }
    for (int idx = tid; idx < Bz * Hz; idx += NTHR)
      h_s[idx >> 10][idx & 1023] = h_g[idx];
    __syncthreads();
    if (tid < 96) {
      int b = tid & 3, g6 = (tid >> 2) % 6, jl = tid / 24;
      int j = jbase + jl;
      float acc;
      if (g6 < 3) {
        int row = g6 * Hz + j;
        acc = enc_bih[row] + dotk(enc_Wih + (long)row * Ez, &x_s[b][0], Ez / 4);
      } else {
        int row = (g6 - 3) * Hz + j;
        acc = enc_bhh[row] + dotk(enc_Whh + (long)row * Hz, &h_s[b][0], Hz / 4);
      }
      g_s[b][g6][jl] = acc;
    }
    __syncthreads();
    if (tid < 16) {
      int b = tid & 3, jl = tid >> 2;
      int j = jbase + jl;
      float r = sigf(g_s[b][0][jl] + g_s[b][3][jl]);
      float z = sigf(g_s[b][1][jl] + g_s[b][4][jl]);
      float n = tanhf(g_s[b][2][jl] + r * g_s[b][5][jl]);
      float hv = (1.0f - z) * n + z * h_s[b][j];
      h_g[b * Hz + j] = hv;
      encout_g[((long)(b * Tz) + t) * Hz + j] = hv;
    }
    gridbar(ctrl, ++epoch);
  }

  // ================= P_t = enc_outs @ W_av_ctx^T (one-time) =================
  {
    int abase = (bid >> 2) * 8;
    int btbase = (bid & 3) * 128;
    for (int it = 0; it < 4; ++it) {
      int idx = it * NTHR + tid;
      int a = abase + (idx >> 7);
      int bt = btbase + (idx & 127);
      int b = bt >> 7, t2 = bt & 127;
      float acc = dotk(W_av + (long)a * (2 * Hz), encout_g + (long)bt * Hz, Hz / 4);
      pt_g[((long)(b * Az) + a) * Tz + t2] = acc;
    }
    gridbar(ctrl, ++epoch);
  }

  // ================= decoder: 512 greedy steps =================
  for (int s = 0; s < NSTEPS; ++s) {
    // ---- D1: ids reduce, stage x/h, GRU ----
    {
      int w = tid >> 6, l = tid & 63;
      u64 best = 0;
#pragma unroll
      for (int gi = 0; gi < 4; ++gi) {
        u64 v = amax_g[(l + gi * 64) * 4 + w];
        best = v > best ? v : best;
      }
      for (int off = 32; off; off >>= 1) {
        u64 o = __shfl_xor(best, off);
        best = o > best ? o : best;
      }
      if (l == 0) ids_s[w] = (int)(0xFFFFFFFFu - (u32)(best & 0xFFFFFFFFull));
    }
    __syncthreads();
    for (int idx = tid; idx < Bz * Ez; idx += NTHR) {
      int b = idx >> 9, k = idx & 511;
      x_s[b][k] = dec_emb[(long)ids_s[b] * Ez + k];
      x_s[b][Ez + k] = av_g[b * Az + k];
    }
    for (int idx = tid; idx < Bz * Hz; idx += NTHR)
      h_s[idx >> 10][idx & 1023] = h_g[idx];
    __syncthreads();
    if (tid < 96) {
      int b = tid & 3, g6 = (tid >> 2) % 6, jl = tid / 24;
      int j = jbase + jl;
      float acc;
      if (g6 < 3) {
        int row = g6 * Hz + j;
        acc = dec_bih[row] + dotk(dec_Wih + (long)row * (Ez + Az), &x_s[b][0], (Ez + Az) / 4);
      } else {
        int row = (g6 - 3) * Hz + j;
        acc = dec_bhh[row] + dotk(dec_Whh + (long)row * Hz, &h_s[b][0], Hz / 4);
      }
      g_s[b][g6][jl] = acc;
    }
    __syncthreads();
    if (tid < 16) {
      int b = tid & 3, jl = tid >> 2;
      int j = jbase + jl;
      float r = sigf(g_s[b][0][jl] + g_s[b][3][jl]);
      float z = sigf(g_s[b][1][jl] + g_s[b][4][jl]);
      float n = tanhf(g_s[b][2][jl] + r * g_s[b][5][jl]);
      h_g[b * Hz + j] = (1.0f - z) * n + z * h_s[b][j];
    }
    gridbar(ctrl, ++epoch);

    // ---- D2: attention scores (blocks 32..63) + Qh = W_av_h @ h (blocks 64..127) ----
    if (bid >= 32 && bid < 128) {
      for (int idx = tid; idx < Bz * Hz; idx += NTHR)
        h_s[idx >> 10][idx & 1023] = h_g[idx];
      __syncthreads();
      if (bid < 64) {
        if (tid < 16) {
          int did = (bid - 32) * 16 + tid;
          int b = did >> 7, t2 = did & 127;
          float acc = dotk(encout_g + (long)(b * Tz + t2) * Hz, &h_s[b][0], Hz / 4);
          score_g[b * Tz + t2] = (inputs[b * Tz + t2] != 0) ? acc : -1e30f;
        }
      } else {
        if (tid < 32) {
          int a = (bid - 64) * 8 + (tid >> 2), b = tid & 3;
          float acc = dotk(W_av + (long)a * (2 * Hz) + Hz, &h_s[b][0], Hz / 4);
          qh_g[b * Az + a] = acc;
        }
      }
    }
    gridbar(ctrl, ++epoch);

    // ---- D3: softmax + attn_vec (blocks 0..63), attn-weight output (block 64) ----
    if (bid < 65) {
      int w = tid >> 6, l = tid & 63;
      {
        float s0 = score_g[w * Tz + l], s1 = score_g[w * Tz + 64 + l];
        float m = fmaxf(s0, s1);
        for (int off = 32; off; off >>= 1) m = fmaxf(m, __shfl_xor(m, off));
        float e0 = expf(s0 - m), e1 = expf(s1 - m);
        float sum = e0 + e1;
        for (int off = 32; off; off >>= 1) sum += __shfl_xor(sum, off);
        e_s[w][l] = e0; e_s[w][64 + l] = e1;
        if (l == 0) sinv_s[w] = 1.0f / sum;
      }
      __syncthreads();
      if (bid < 64) {
        if (tid < 32) {
          int a = bid * 8 + (tid >> 2), b = tid & 3;
          const float4* p4 = (const float4*)(pt_g + ((long)(b * Az) + a) * Tz);
          const float4* e4 = (const float4*)&e_s[b][0];
          float4 a0 = make_float4(0.f, 0.f, 0.f, 0.f), a1 = a0;
          for (int i = 0; i < 32; i += 2) {
            float4 ev0 = e4[i], pv0 = p4[i];
            float4 ev1 = e4[i + 1], pv1 = p4[i + 1];
            a0.x += ev0.x * pv0.x; a0.y += ev0.y * pv0.y; a0.z += ev0.z * pv0.z; a0.w += ev0.w * pv0.w;
            a1.x += ev1.x * pv1.x; a1.y += ev1.y * pv1.y; a1.z += ev1.z * pv1.z; a1.w += ev1.w * pv1.w;
          }
          float d = (a0.x + a1.x) + (a0.y + a1.y) + (a0.z + a1.z) + (a0.w + a1.w);
          float av = tanhf(d * sinv_s[b] + qh_g[b * Az + a] + b_av[a]);
          av_g[b * Az + a] = av;
        }
      } else { // bid == 64: emit attention weights
        for (int idx = tid; idx < Bz * Tz; idx += NTHR) {
          int b = idx >> 7;
          out_aw[(long)s * Bz * Tz + idx] = e_s[b][idx & 127] * sinv_s[b];
        }
      }
    }
    gridbar(ctrl, ++epoch);

    // ---- D4: logits = W_cls @ attn_vec + b_cls, write + block-local argmax ----
    {
      for (int idx = tid; idx < Bz * Az; idx += NTHR)
        at_s[idx >> 9][idx & 511] = av_g[idx];
      __syncthreads();
      int nrows = 62 + (bid < 128 ? 1 : 0);
      int rbase = bid * 62 + (bid < 128 ? bid : 128);
      int rl = tid >> 2, b = tid & 3;
      if (rl < nrows) {
        int row = rbase + rl;
        float acc = b_cls[row] + dotk(W_cls + (long)row * Az, &at_s[b][0], Az / 4);
        out_pred[((long)s * Bz + b) * Vz + row] = acc;
        u32 u = __float_as_uint(acc);
        u = (u & 0x80000000u) ? ~u : (u | 0x80000000u);
        am_s[b][rl] = ((u64)u << 32) | (u64)(0xFFFFFFFFu - (u32)row);
      }
      __syncthreads();
      {
        int w = tid >> 6, l = tid & 63;
        u64 best = (l < nrows) ? am_s[w][l] : 0ull;
        for (int off = 32; off; off >>= 1) {
          u64 o = __shfl_xor(best, off);
          best = o > best ? o : best;
        }
        if (l == 0) amax_g[bid * 4 + w] = best;
      }
    }
    gridbar(ctrl, ++epoch);
  }
}

extern "C" void kernel_launch(void* const* d_in, const int* in_sizes, int n_in,
                              void* d_out, int out_size, void* d_ws, size_t ws_size,
                              hipStream_t stream) {
  const int* inputs = (const int*)d_in[0];
  const float* enc_emb = (const float*)d_in[1];
  const float* enc_Wih = (const float*)d_in[2];
  const float* enc_Whh = (const float*)d_in[3];
  const float* enc_bih = (const float*)d_in[4];
  const float* enc_bhh = (const float*)d_in[5];
  const float* dec_emb = (const float*)d_in[6];
  const float* dec_Wih = (const float*)d_in[7];
  const float* dec_Whh = (const float*)d_in[8];
  const float* dec_bih = (const float*)d_in[9];
  const float* dec_bhh = (const float*)d_in[10];
  const float* W_av = (const float*)d_in[11];
  const float* b_av = (const float*)d_in[12];
  const float* W_cls = (const float*)d_in[13];
  const float* b_cls = (const float*)d_in[14];

  // zero barrier state + h + attn_vec; set argmax partials so step-0 ids decode to 0
  hipMemsetAsync(d_ws, 0, 40960, stream);
  hipMemsetAsync((char*)d_ws + 40960, 0xFF, 8192, stream);

  seq2seq_kernel<<<dim3(NBLK), dim3(NTHR), 0, stream>>>(
      inputs, enc_emb, enc_Wih, enc_Whh, enc_bih, enc_bhh,
      dec_emb, dec_Wih, dec_Whh, dec_bih, dec_bhh,
      W_av, b_av, W_cls, b_cls,
      (float*)d_out, (char*)d_ws);
}

// Round 2
// 58684.247 us; speedup vs baseline: 1.6401x; 1.6401x over previous
//
#include <hip/hip_runtime.h>
#include <stdint.h>

typedef unsigned int u32;
typedef unsigned long long u64;

#define NBLK 256
#define NTHR 1024
#define Bz 4
#define Tz 128
#define Hz 1024
#define Ez 512
#define Az 512
#define Vz 16000
#define NSTEPS 512
#define XS 1032   // LDS row stride (floats); 1032*4 bytes is 16B-aligned

// ---------------- ws layout (bytes) ----------------
// [0,      16384)  ctrl u32s: grp[g] @ u32 idx g*16 (g<16), root @ 256, gen @ 320
// [16384,  32768)  h      [4][1024] f32
// [32768,  40960)  attn   [4][512]  f32
// [40960,  49152)  amax   [256][4]  u64
// [49152,  51200)  score  [4][128]  f32
// [51200,  59392)  qh     [4][512]  f32
// [59392, +2MB)    enc_outs [4][128][1024] f32
// then             P_t    [4][512][128] f32

__device__ __forceinline__ float sigf(float x) { return 1.0f / (1.0f + expf(-x)); }

// interleaved k-split dot: lane owns float4 chunks {lane + L*k : k<K}
template <int K, int L>
__device__ __forceinline__ float idot(const float4* __restrict__ w4,
                                      const float4* __restrict__ v4, int lane) {
  float4 acc = make_float4(0.f, 0.f, 0.f, 0.f);
#pragma unroll 8
  for (int k = 0; k < K; ++k) {
    float4 a = w4[lane + L * k];
    float4 b = v4[lane + L * k];
    acc.x += a.x * b.x; acc.y += a.y * b.y; acc.z += a.z * b.z; acc.w += a.w * b.w;
  }
  return (acc.x + acc.y) + (acc.z + acc.w);
}

// two-level grid barrier, monotonic epochs (state zeroed by hipMemsetAsync before launch)
__device__ __forceinline__ void gridbar(u32* ctrl, int epoch) {
  __syncthreads();
  if (threadIdx.x == 0) {
    const u32 target = (u32)epoch * 16u;
    u32* grp = ctrl + ((blockIdx.x >> 4) * 16);
    u32 v = __hip_atomic_fetch_add(grp, 1u, __ATOMIC_ACQ_REL, __HIP_MEMORY_SCOPE_AGENT);
    if (v == target - 1u) {
      u32 r = __hip_atomic_fetch_add(ctrl + 256, 1u, __ATOMIC_ACQ_REL, __HIP_MEMORY_SCOPE_AGENT);
      if (r == target - 1u)
        __hip_atomic_store(ctrl + 320, (u32)epoch, __ATOMIC_RELEASE, __HIP_MEMORY_SCOPE_AGENT);
    }
    while (__hip_atomic_load(ctrl + 320, __ATOMIC_ACQUIRE, __HIP_MEMORY_SCOPE_AGENT) < (u32)epoch)
      __builtin_amdgcn_s_sleep(1);
  }
  __syncthreads();
}

__global__ void __launch_bounds__(NTHR, 1) seq2seq_kernel(
    const int* __restrict__ inputs,
    const float* __restrict__ enc_emb, const float* __restrict__ enc_Wih,
    const float* __restrict__ enc_Whh, const float* __restrict__ enc_bih,
    const float* __restrict__ enc_bhh,
    const float* __restrict__ dec_emb, const float* __restrict__ dec_Wih,
    const float* __restrict__ dec_Whh, const float* __restrict__ dec_bih,
    const float* __restrict__ dec_bhh,
    const float* __restrict__ W_av, const float* __restrict__ b_av,
    const float* __restrict__ W_cls, const float* __restrict__ b_cls,
    float* __restrict__ out, char* __restrict__ ws) {
  const int tid = threadIdx.x;
  const int bid = blockIdx.x;

  u32* ctrl = (u32*)ws;
  float* h_g = (float*)(ws + 16384);
  float* av_g = (float*)(ws + 32768);
  u64* amax_g = (u64*)(ws + 40960);
  float* score_g = (float*)(ws + 49152);
  float* qh_g = (float*)(ws + 51200);
  float* encout_g = (float*)(ws + 59392);
  float* pt_g = encout_g + Bz * Tz * Hz;
  float* out_pred = out;                        // [512][4][16000]
  float* out_aw = out + (long)NSTEPS * Bz * Vz; // [512][4][128]

  __shared__ __align__(16) float x_s[Bz][XS];
  __shared__ __align__(16) float h_s[Bz][XS];
  __shared__ __align__(16) float at_s[Bz][520];
  __shared__ __align__(16) float e_s[Bz][132];
  __shared__ float g_s[Bz][6][4];
  __shared__ float sinv_s[Bz];
  __shared__ int ids_s[Bz];
  __shared__ u64 am_s[Bz][64];

  int epoch = 0;
  const int jbase = bid * 4;         // this block's 4 hidden dims
  const int t8 = tid >> 3, l8 = tid & 7;
  // GRU task map (t8<96), b-uniform per wave: tasks 0..23 -> b=0, 24..47 -> b=1, ...
  const int b8 = t8 / 24;
  const int r6 = t8 % 24;
  const int g6 = r6 >> 2, jl = r6 & 3;

  // ================= encoder: 128 GRU steps =================
  for (int t = 0; t < Tz; ++t) {
    for (int idx = tid; idx < Bz * Ez; idx += NTHR) {
      int b = idx >> 9, k = idx & 511;
      x_s[b][k] = enc_emb[(long)inputs[b * Tz + t] * Ez + k];
    }
    for (int idx = tid; idx < Bz * Hz; idx += NTHR)
      h_s[idx >> 10][idx & 1023] = h_g[idx];
    __syncthreads();
    if (t8 < 96) {
      int j = jbase + jl;
      if (g6 < 3) {
        int row = g6 * Hz + j;
        float acc = idot<Ez / 32, 8>((const float4*)(enc_Wih + (long)row * Ez),
                                     (const float4*)&x_s[b8][0], l8);
        acc += __shfl_xor(acc, 1); acc += __shfl_xor(acc, 2); acc += __shfl_xor(acc, 4);
        if (l8 == 0) g_s[b8][g6][jl] = acc + enc_bih[row];
      } else {
        int row = (g6 - 3) * Hz + j;
        float acc = idot<Hz / 32, 8>((const float4*)(enc_Whh + (long)row * Hz),
                                     (const float4*)&h_s[b8][0], l8);
        acc += __shfl_xor(acc, 1); acc += __shfl_xor(acc, 2); acc += __shfl_xor(acc, 4);
        if (l8 == 0) g_s[b8][g6][jl] = acc + enc_bhh[row];
      }
    }
    __syncthreads();
    if (tid < 16) {
      int b = tid & 3, jj = tid >> 2;
      int j = jbase + jj;
      float r = sigf(g_s[b][0][jj] + g_s[b][3][jj]);
      float z = sigf(g_s[b][1][jj] + g_s[b][4][jj]);
      float n = tanhf(g_s[b][2][jj] + r * g_s[b][5][jj]);
      float hv = (1.0f - z) * n + z * h_s[b][j];
      h_g[b * Hz + j] = hv;
      encout_g[((long)(b * Tz) + t) * Hz + j] = hv;
    }
    gridbar(ctrl, ++epoch);
  }

  // ================= P_t = enc_outs @ W_av_ctx^T (one-time) =================
  {
    int a = (bid >> 2) * 8 + (tid >> 7);
    int bt = (bid & 3) * 128 + (tid & 127);
    int b = bt >> 7, t2 = bt & 127;
    float acc = idot<256, 1>((const float4*)(W_av + (long)a * (2 * Hz)),
                             (const float4*)(encout_g + (long)bt * Hz), 0);
    pt_g[((long)(b * Az) + a) * Tz + t2] = acc;
    gridbar(ctrl, ++epoch);
  }

  // ================= decoder: 512 greedy steps =================
  for (int s = 0; s < NSTEPS; ++s) {
    // ---- D1: argmax gather -> ids, stage x/h, GRU ----
    if (tid < 256) {
      int b = tid >> 6, l = tid & 63;
      u64 best = 0;
#pragma unroll
      for (int g = 0; g < 4; ++g) {
        u64 v = amax_g[(l + 64 * g) * 4 + b];
        best = v > best ? v : best;
      }
      for (int off = 32; off; off >>= 1) {
        u64 o = __shfl_xor(best, off);
        best = o > best ? o : best;
      }
      if (l == 0) ids_s[b] = (int)(0xFFFFFFFFu - (u32)(best & 0xFFFFFFFFull));
    }
    __syncthreads();
    for (int idx = tid; idx < Bz * (Ez + Az); idx += NTHR) {
      int b = idx >> 10, k = idx & 1023;
      x_s[b][k] = (k < Ez) ? dec_emb[(long)ids_s[b] * Ez + k] : av_g[b * Az + (k - Ez)];
    }
    for (int idx = tid; idx < Bz * Hz; idx += NTHR)
      h_s[idx >> 10][idx & 1023] = h_g[idx];
    __syncthreads();
    if (t8 < 96) {
      int gm = (g6 < 3) ? g6 : g6 - 3;
      int row = gm * Hz + jbase + jl;
      const float4* w4 = (const float4*)(((g6 < 3) ? dec_Wih : dec_Whh) + (long)row * 1024);
      const float4* v4 = (const float4*)((g6 < 3) ? &x_s[b8][0] : &h_s[b8][0]);
      float acc = idot<32, 8>(w4, v4, l8);
      acc += __shfl_xor(acc, 1); acc += __shfl_xor(acc, 2); acc += __shfl_xor(acc, 4);
      if (l8 == 0)
        g_s[b8][g6][jl] = acc + ((g6 < 3) ? dec_bih[row] : dec_bhh[row]);
    }
    __syncthreads();
    if (tid < 16) {
      int b = tid & 3, jj = tid >> 2;
      int j = jbase + jj;
      float r = sigf(g_s[b][0][jj] + g_s[b][3][jj]);
      float z = sigf(g_s[b][1][jj] + g_s[b][4][jj]);
      float n = tanhf(g_s[b][2][jj] + r * g_s[b][5][jj]);
      h_g[b * Hz + j] = (1.0f - z) * n + z * h_s[b][j];
    }
    gridbar(ctrl, ++epoch);

    // ---- D2: scores (waves 0..511) + qh (waves 512..2559), 64 lanes per dot ----
    {
      const int wv = tid >> 6, lane = tid & 63;
      const int gw = bid * 16 + wv;
      if (gw < 512) {
        int b = gw >> 7, t = gw & 127;
        float acc = idot<4, 64>((const float4*)(encout_g + (long)(b * Tz + t) * Hz),
                                (const float4*)(h_g + b * Hz), lane);
#pragma unroll
        for (int off = 32; off; off >>= 1) acc += __shfl_xor(acc, off);
        if (lane == 0)
          score_g[b * Tz + t] = (inputs[b * Tz + t] != 0) ? acc : -1e30f;
      } else if (gw < 2560) {
        int g = gw - 512, a = g >> 2, b = g & 3;
        float acc = idot<4, 64>((const float4*)(W_av + (long)a * (2 * Hz) + Hz),
                                (const float4*)(h_g + b * Hz), lane);
#pragma unroll
        for (int off = 32; off; off >>= 1) acc += __shfl_xor(acc, off);
        if (lane == 0) qh_g[b * Az + a] = acc;
      }
    }
    gridbar(ctrl, ++epoch);

    // ---- D3: softmax (redundant in blocks 0..16) + attn_vec (0..15) + aw out (16) ----
    if (bid <= 16) {
      if (tid < 256) {
        int b = tid >> 6, l = tid & 63;
        float s0 = score_g[b * Tz + l], s1 = score_g[b * Tz + 64 + l];
        float m = fmaxf(s0, s1);
#pragma unroll
        for (int off = 32; off; off >>= 1) m = fmaxf(m, __shfl_xor(m, off));
        float e0 = expf(s0 - m), e1 = expf(s1 - m);
        float sum = e0 + e1;
#pragma unroll
        for (int off = 32; off; off >>= 1) sum += __shfl_xor(sum, off);
        e_s[b][l] = e0; e_s[b][64 + l] = e1;
        if (l == 0) sinv_s[b] = 1.0f / sum;
      }
      __syncthreads();
      if (bid < 16) {
        int g = bid * 128 + t8;
        int b = g >> 9, a = g & 511;
        float acc = idot<4, 8>((const float4*)(pt_g + ((long)(b * Az) + a) * Tz),
                               (const float4*)&e_s[b][0], l8);
        acc += __shfl_xor(acc, 1); acc += __shfl_xor(acc, 2); acc += __shfl_xor(acc, 4);
        if (l8 == 0)
          av_g[b * Az + a] = tanhf(acc * sinv_s[b] + qh_g[b * Az + a] + b_av[a]);
      } else {
        if (tid < Bz * Tz) {
          int b = tid >> 7;
          out_aw[(long)s * Bz * Tz + tid] = e_s[b][tid & 127] * sinv_s[b];
        }
      }
    }
    gridbar(ctrl, ++epoch);

    // ---- D4: logits + block-local argmax (4 lanes per row-dot) ----
    {
      for (int idx = tid; idx < Bz * Az; idx += NTHR)
        at_s[idx >> 9][idx & 511] = av_g[idx];
      __syncthreads();
      const int task = tid >> 2, l4 = tid & 3;
      const int b = task >> 6, rl = task & 63;   // b-uniform waves
      const int nrows = 62 + (bid < 128 ? 1 : 0);
      const int rbase = bid * 62 + (bid < 128 ? bid : 128);
      if (rl < nrows) {
        int row = rbase + rl;
        float acc = idot<32, 4>((const float4*)(W_cls + (long)row * Az),
                                (const float4*)&at_s[b][0], l4);
        acc += __shfl_xor(acc, 1); acc += __shfl_xor(acc, 2);
        if (l4 == 0) {
          acc += b_cls[row];
          out_pred[((long)s * Bz + b) * Vz + row] = acc;
          u32 u = __float_as_uint(acc);
          u = (u & 0x80000000u) ? ~u : (u | 0x80000000u);
          am_s[b][rl] = ((u64)u << 32) | (u64)(0xFFFFFFFFu - (u32)row);
        }
      }
      __syncthreads();
      if (tid < 256) {
        int b2 = tid >> 6, l = tid & 63;
        u64 best = (l < nrows) ? am_s[b2][l] : 0ull;
        for (int off = 32; off; off >>= 1) {
          u64 o = __shfl_xor(best, off);
          best = o > best ? o : best;
        }
        if (l == 0) amax_g[bid * 4 + b2] = best;
      }
    }
    gridbar(ctrl, ++epoch);
  }
}

extern "C" void kernel_launch(void* const* d_in, const int* in_sizes, int n_in,
                              void* d_out, int out_size, void* d_ws, size_t ws_size,
                              hipStream_t stream) {
  const int* inputs = (const int*)d_in[0];
  const float* enc_emb = (const float*)d_in[1];
  const float* enc_Wih = (const float*)d_in[2];
  const float* enc_Whh = (const float*)d_in[3];
  const float* enc_bih = (const float*)d_in[4];
  const float* enc_bhh = (const float*)d_in[5];
  const float* dec_emb = (const float*)d_in[6];
  const float* dec_Wih = (const float*)d_in[7];
  const float* dec_Whh = (const float*)d_in[8];
  const float* dec_bih = (const float*)d_in[9];
  const float* dec_bhh = (const float*)d_in[10];
  const float* W_av = (const float*)d_in[11];
  const float* b_av = (const float*)d_in[12];
  const float* W_cls = (const float*)d_in[13];
  const float* b_cls = (const float*)d_in[14];

  // zero barrier state + h + attn_vec; 0xFF argmax partials so step-0 ids decode to 0
  hipMemsetAsync(d_ws, 0, 40960, stream);
  hipMemsetAsync((char*)d_ws + 40960, 0xFF, 8192, stream);

  seq2seq_kernel<<<dim3(NBLK), dim3(NTHR), 0, stream>>>(
      inputs, enc_emb, enc_Wih, enc_Whh, enc_bih, enc_bhh,
      dec_emb, dec_Wih, dec_Whh, dec_bih, dec_bhh,
      W_av, b_av, W_cls, b_cls,
      (float*)d_out, (char*)d_ws);
}